// Round 4
// baseline (560.296 us; speedup 1.0000x reference)
//
#include <hip/hip_runtime.h>
#include <stdint.h>

// ---------------------------------------------------------------------------
// QuantLinear via EXACT int8 path:
//   qx[t,k] int8, sx[t,g] (g=k/128) ; qw[o,k] int8, sw[o]
//   out[t,o] = sw[o] * sum_g sx[t,g] * (int dot over group g) + bias[o]
// R7: back to the proven 128x128 / 4-wave / BK=128 geometry (R3, 218us) with
// ONE structural fix: double-buffered LDS (64KB -> 2 blocks/CU) and
// issue-early/drain-late staging (stage j+1 + scale prefetch issued right
// after the per-tile barrier; drained at the top of iter j+1 when ~1 tile
// old). One barrier per K-tile. x2-unrolled loop for static buffer/scale
// ping-pong. Deferred it[] fold. Quant kernels unchanged.
// ---------------------------------------------------------------------------

typedef __attribute__((ext_vector_type(4))) int   i32x4;
typedef __attribute__((ext_vector_type(4))) float f32x4;

static __device__ __forceinline__ void load_lds16(const void* g, void* l) {
    __builtin_amdgcn_global_load_lds(
        (const __attribute__((address_space(1))) void*)g,
        (__attribute__((address_space(3))) void*)l, 16, 0, 0);
}

static __device__ __forceinline__ int8_t q8m(float v, float inv) {
    float q = rintf(v * inv);                   // half-even, matches np
    q = fminf(fmaxf(q, -128.0f), 127.0f);
    return (int8_t)(int)q;
}

// ---------------- act quant: one row per block -----------------------------
__global__ __launch_bounds__(256) void quant_act_kernel(
        const float* __restrict__ x, int8_t* __restrict__ xq,
        float* __restrict__ sxT, int M) {
    const int row = blockIdx.x, t = threadIdx.x;
    const float* xr = x + (size_t)row * 4096;
    float4 v[4];
#pragma unroll
    for (int i = 0; i < 4; i++)
        v[i] = *(const float4*)(xr + t * 16 + i * 4);
    float m = 0.0f;
#pragma unroll
    for (int i = 0; i < 4; i++)
        m = fmaxf(m, fmaxf(fmaxf(fabsf(v[i].x), fabsf(v[i].y)),
                           fmaxf(fabsf(v[i].z), fabsf(v[i].w))));
    m = fmaxf(m, __shfl_xor(m, 1));
    m = fmaxf(m, __shfl_xor(m, 2));
    m = fmaxf(m, __shfl_xor(m, 4));
    const float scale = fmaxf(m / 127.0f, 1e-8f);
    const float inv = 1.0f / scale;
    union { int8_t b[16]; i32x4 w; } o;
#pragma unroll
    for (int i = 0; i < 4; i++) {
        o.b[i * 4 + 0] = q8m(v[i].x, inv);
        o.b[i * 4 + 1] = q8m(v[i].y, inv);
        o.b[i * 4 + 2] = q8m(v[i].z, inv);
        o.b[i * 4 + 3] = q8m(v[i].w, inv);
    }
    *(i32x4*)(xq + (size_t)row * 4096 + t * 16) = o.w;
    if ((t & 7) == 0)                       // sxT layout [G, M]
        sxT[(size_t)(t >> 3) * M + row] = scale;
}

// ---------------- weight quant: one row per block, per-row scale -----------
__global__ __launch_bounds__(256) void quant_wgt_kernel(
        const float* __restrict__ w, int8_t* __restrict__ wq,
        float* __restrict__ sw) {
    const int row = blockIdx.x, t = threadIdx.x;
    const float* wr = w + (size_t)row * 4096;
    float4 v[4];
#pragma unroll
    for (int i = 0; i < 4; i++)
        v[i] = *(const float4*)(wr + t * 16 + i * 4);
    float m = 0.0f;
#pragma unroll
    for (int i = 0; i < 4; i++)
        m = fmaxf(m, fmaxf(fmaxf(fabsf(v[i].x), fabsf(v[i].y)),
                           fmaxf(fabsf(v[i].z), fabsf(v[i].w))));
#pragma unroll
    for (int off = 1; off < 64; off <<= 1)
        m = fmaxf(m, __shfl_xor(m, off));
    __shared__ float wm[4];
    if ((t & 63) == 0) wm[t >> 6] = m;
    __syncthreads();
    m = fmaxf(fmaxf(wm[0], wm[1]), fmaxf(wm[2], wm[3]));
    const float scale = fmaxf(m / 127.0f, 1e-8f);
    if (t == 0) sw[row] = scale;
    const float inv = 1.0f / scale;
    union { int8_t b[16]; i32x4 w4; } o;
#pragma unroll
    for (int i = 0; i < 4; i++) {
        o.b[i * 4 + 0] = q8m(v[i].x, inv);
        o.b[i * 4 + 1] = q8m(v[i].y, inv);
        o.b[i * 4 + 2] = q8m(v[i].z, inv);
        o.b[i * 4 + 3] = q8m(v[i].w, inv);
    }
    *(i32x4*)(wq + (size_t)row * 4096 + t * 16) = o.w4;
}

// ---------------- int8 GEMM: 128x128, dbuf, issue-early/drain-late ---------
// LDS image (per buffer): row r (128 rows, 128 B), 16B chunk c at byte
// r*128 + (c ^ (r&7))*16 (staging lanes fetch permuted global chunks; DMA
// dest linear). Iter j: {vmcnt(0) [stage j is ~1 tile old]; barrier;
// stage j+1 -> buf^1 (8 calls); prefetch sx(j+1) regs; ds_read 16xb128 from
// buf; compute 32 MFMA with deferred it[] fold}. One barrier per K-tile:
// reads of buf^1 (iter j-1) retired via each wave's lgkm wait before it
// reached this barrier, so post-barrier staging may overwrite buf^1.
#define ITER(CUR, SXC, SXN, J)                                               \
    {                                                                        \
        asm volatile("s_waitcnt vmcnt(0)" ::: "memory");                     \
        __builtin_amdgcn_s_barrier();                                        \
        const int jn = ((J) + 1 < NT) ? (J) + 1 : (J);                       \
        const size_t kn = (size_t)jn << 7;                                   \
        load_lds16(Ag + kn,            &As[(CUR) ^ 1][sldsw]);               \
        load_lds16(Ag + kn + 32 * sK,  &As[(CUR) ^ 1][32 * 128 + sldsw]);    \
        load_lds16(Ag + kn + 64 * sK,  &As[(CUR) ^ 1][64 * 128 + sldsw]);    \
        load_lds16(Ag + kn + 96 * sK,  &As[(CUR) ^ 1][96 * 128 + sldsw]);    \
        load_lds16(Bg + kn,            &Bs[(CUR) ^ 1][sldsw]);               \
        load_lds16(Bg + kn + 32 * sK,  &Bs[(CUR) ^ 1][32 * 128 + sldsw]);    \
        load_lds16(Bg + kn + 64 * sK,  &Bs[(CUR) ^ 1][64 * 128 + sldsw]);    \
        load_lds16(Bg + kn + 96 * sK,  &Bs[(CUR) ^ 1][96 * 128 + sldsw]);    \
        _Pragma("unroll")                                                    \
        for (int mi = 0; mi < 4; ++mi)                                       \
            SXN[mi] = *(const f32x4*)(sxg + (size_t)jn * M + mi * 16);       \
        i32x4 a[4][2], b[4][2];                                              \
        _Pragma("unroll")                                                    \
        for (int mi = 0; mi < 4; ++mi) {                                     \
            const int arow = wm + mi * 16 + fr;                              \
            const int brow = wn + mi * 16 + fr;                              \
            _Pragma("unroll")                                                \
            for (int h = 0; h < 2; ++h) {                                    \
                a[mi][h] = *(const i32x4*)(As[CUR] + arow * 128 +            \
                                           (((h * 4 + q) ^ r7) << 4));       \
                b[mi][h] = *(const i32x4*)(Bs[CUR] + brow * 128 +            \
                                           (((h * 4 + q) ^ r7) << 4));       \
            }                                                                \
        }                                                                    \
        __builtin_amdgcn_sched_barrier(0);                                   \
        _Pragma("unroll")                                                    \
        for (int ni = 0; ni < 4; ++ni) {                                     \
            i32x4 it[4];                                                     \
            _Pragma("unroll")                                                \
            for (int mi = 0; mi < 4; ++mi) {                                 \
                it[mi] = __builtin_amdgcn_mfma_i32_16x16x64_i8(              \
                    a[mi][0], b[ni][0], (i32x4){0, 0, 0, 0}, 0, 0, 0);       \
                it[mi] = __builtin_amdgcn_mfma_i32_16x16x64_i8(              \
                    a[mi][1], b[ni][1], it[mi], 0, 0, 0);                    \
            }                                                                \
            _Pragma("unroll")                                                \
            for (int mi = 0; mi < 4; ++mi)                                   \
                _Pragma("unroll")                                            \
                for (int r = 0; r < 4; ++r)                                  \
                    acc[mi][ni][r] += (float)it[mi][r] * SXC[mi][r];         \
        }                                                                    \
    }

__global__ __launch_bounds__(256, 2) void gemm_i8_kernel(
        const int8_t* __restrict__ A, const int8_t* __restrict__ B,
        const float* __restrict__ sxT, const float* __restrict__ sw,
        const float* __restrict__ bias, float* __restrict__ C,
        int M, int N, int K) {
    __shared__ __align__(16) int8_t As[2][128 * 128];   // 32 KB
    __shared__ __align__(16) int8_t Bs[2][128 * 128];   // 32 KB
    const int tid = threadIdx.x;
    const int wave = tid >> 6, lane = tid & 63;

    // bijective XCD swizzle (nwg = 2048, %8 == 0)
    const int nwg = gridDim.x, nN = N >> 7;
    const int wg = ((int)blockIdx.x & 7) * (nwg >> 3) + ((int)blockIdx.x >> 3);
    const int bm = (wg / nN) << 7, bn = (wg % nN) << 7;

    const int wm = (wave >> 1) << 6, wn = (wave & 1) << 6;   // 64x64 / wave
    const int fr = lane & 15, q = lane >> 4, r7 = lane & 7;

    // staging: call i covers rows i*32 + wave*8 + (lane>>3);
    // lane fetches global chunk (lane&7)^((lane>>3)&7) -> XOR-swizzled LDS.
    const int srow = wave * 8 + (lane >> 3);
    const int scol = ((lane & 7) ^ ((lane >> 3) & 7)) << 4;
    const size_t sK = (size_t)K;
    const int8_t* Ag = A + (size_t)(bm + srow) * sK + scol;
    const int8_t* Bg = B + (size_t)(bn + srow) * sK + scol;
    const int sldsw = wave * 8 * 128;   // wave-uniform LDS base per call

    f32x4 acc[4][4];
#pragma unroll
    for (int i = 0; i < 4; i++)
#pragma unroll
        for (int jn2 = 0; jn2 < 4; jn2++) acc[i][jn2] = (f32x4){0.f, 0.f, 0.f, 0.f};

    const float* sxg = sxT + bm + wm + q * 4;   // + j*M per tile
    const int NT = K >> 7;

    // prologue: stage tile 0 -> buf 0; load sx(0)
    load_lds16(Ag,            &As[0][sldsw]);
    load_lds16(Ag + 32 * sK,  &As[0][32 * 128 + sldsw]);
    load_lds16(Ag + 64 * sK,  &As[0][64 * 128 + sldsw]);
    load_lds16(Ag + 96 * sK,  &As[0][96 * 128 + sldsw]);
    load_lds16(Bg,            &Bs[0][sldsw]);
    load_lds16(Bg + 32 * sK,  &Bs[0][32 * 128 + sldsw]);
    load_lds16(Bg + 64 * sK,  &Bs[0][64 * 128 + sldsw]);
    load_lds16(Bg + 96 * sK,  &Bs[0][96 * 128 + sldsw]);
    f32x4 sxa[4], sxb[4];
#pragma unroll
    for (int mi = 0; mi < 4; ++mi)
        sxa[mi] = *(const f32x4*)(sxg + mi * 16);

    for (int j = 0; j < NT; j += 2) {
        ITER(0, sxa, sxb, j)       // compute tile j from buf0; stage j+1->buf1
        ITER(1, sxb, sxa, j + 1)   // compute tile j+1 from buf1; stage ->buf0
    }
    asm volatile("s_waitcnt vmcnt(0)" ::: "memory");  // drain dangling stage

    // epilogue: C/D layout col=lane&15, row=(lane>>4)*4+reg; fold sw + bias
    const int or0 = bm + wm + q * 4;
    const int oc0 = bn + wn + fr;
    float swv[4], bv[4];
#pragma unroll
    for (int ni = 0; ni < 4; ni++) {
        swv[ni] = sw[oc0 + ni * 16];
        bv[ni] = bias[oc0 + ni * 16];
    }
#pragma unroll
    for (int mi = 0; mi < 4; mi++)
#pragma unroll
        for (int ni = 0; ni < 4; ni++)
#pragma unroll
            for (int r = 0; r < 4; r++)
                C[(size_t)(or0 + mi * 16 + r) * N + (oc0 + ni * 16)] =
                    acc[mi][ni][r] * swv[ni] + bv[ni];
}

extern "C" void kernel_launch(void* const* d_in, const int* in_sizes, int n_in,
                              void* d_out, int out_size, void* d_ws, size_t ws_size,
                              hipStream_t stream) {
    const float* x    = (const float*)d_in[0];
    const float* w    = (const float*)d_in[1];
    const float* bias = (const float*)d_in[2];
    // d_in[3] = group_size (128) — hard-assumed.

    const int out_f  = in_sizes[2];
    const int in_f   = in_sizes[1] / out_f;   // 4096
    const int tokens = in_sizes[0] / in_f;
    const int G = in_f / 128;

    int8_t* xq  = (int8_t*)d_ws;                         // [M,K] int8
    int8_t* wq  = xq + (size_t)tokens * in_f;            // [N,K] int8
    float*  sxT = (float*)(wq + (size_t)out_f * in_f);   // [G,M] fp32
    float*  sw  = sxT + (size_t)G * tokens;              // [N]  fp32
    float*  out = (float*)d_out;

    quant_act_kernel<<<tokens, 256, 0, stream>>>(x, xq, sxT, tokens);
    quant_wgt_kernel<<<out_f, 256, 0, stream>>>(w, wq, sw);

    const int nwg = (tokens / 128) * (out_f / 128);      // 2048, %8 == 0
    gemm_i8_kernel<<<nwg, 256, 0, stream>>>(xq, wq, sxT, sw, bias, out,
                                            tokens, out_f, in_f);
}

// Round 5
// 497.625 us; speedup vs baseline: 1.1259x; 1.1259x over previous
//
#include <hip/hip_runtime.h>
#include <stdint.h>

// ---------------------------------------------------------------------------
// QuantLinear via EXACT int8 path:
//   qx[t,k] int8, sx[t,g] (g=k/128) ; qw[o,k] int8, sw[o]
//   out[t,o] = sw[o] * sum_g sx[t,g] * (int dot over group g) + bias[o]
// R8: R3's exact geometry (128x128, 4 waves, BK=128, 32KB single-buffer LDS,
// 2D grid - NO XCD swizzle: R7 proved chunked swizzle triples HBM traffic)
// with ONE surgical reorder: per iter {ds_read j; sync; stage-issue j+1 +
// scale prefetch; MFMA+fold j (hides DMA); sync(vmcnt0 drain)}. R3 drained
// the DMA immediately after issue - full latency exposed each K-tile.
// Scales ping-pong in regs via x2 unroll. Quant kernels unchanged.
// ---------------------------------------------------------------------------

typedef __attribute__((ext_vector_type(4))) int   i32x4;
typedef __attribute__((ext_vector_type(4))) float f32x4;

static __device__ __forceinline__ void load_lds16(const void* g, void* l) {
    __builtin_amdgcn_global_load_lds(
        (const __attribute__((address_space(1))) void*)g,
        (__attribute__((address_space(3))) void*)l, 16, 0, 0);
}

static __device__ __forceinline__ int8_t q8m(float v, float inv) {
    float q = rintf(v * inv);                   // half-even, matches np
    q = fminf(fmaxf(q, -128.0f), 127.0f);
    return (int8_t)(int)q;
}

// ---------------- act quant: one row per block -----------------------------
__global__ __launch_bounds__(256) void quant_act_kernel(
        const float* __restrict__ x, int8_t* __restrict__ xq,
        float* __restrict__ sxT, int M) {
    const int row = blockIdx.x, t = threadIdx.x;
    const float* xr = x + (size_t)row * 4096;
    float4 v[4];
#pragma unroll
    for (int i = 0; i < 4; i++)
        v[i] = *(const float4*)(xr + t * 16 + i * 4);
    float m = 0.0f;
#pragma unroll
    for (int i = 0; i < 4; i++)
        m = fmaxf(m, fmaxf(fmaxf(fabsf(v[i].x), fabsf(v[i].y)),
                           fmaxf(fabsf(v[i].z), fabsf(v[i].w))));
    m = fmaxf(m, __shfl_xor(m, 1));
    m = fmaxf(m, __shfl_xor(m, 2));
    m = fmaxf(m, __shfl_xor(m, 4));
    const float scale = fmaxf(m / 127.0f, 1e-8f);
    const float inv = 1.0f / scale;
    union { int8_t b[16]; i32x4 w; } o;
#pragma unroll
    for (int i = 0; i < 4; i++) {
        o.b[i * 4 + 0] = q8m(v[i].x, inv);
        o.b[i * 4 + 1] = q8m(v[i].y, inv);
        o.b[i * 4 + 2] = q8m(v[i].z, inv);
        o.b[i * 4 + 3] = q8m(v[i].w, inv);
    }
    *(i32x4*)(xq + (size_t)row * 4096 + t * 16) = o.w;
    if ((t & 7) == 0)                       // sxT layout [G, M]
        sxT[(size_t)(t >> 3) * M + row] = scale;
}

// ---------------- weight quant: one row per block, per-row scale -----------
__global__ __launch_bounds__(256) void quant_wgt_kernel(
        const float* __restrict__ w, int8_t* __restrict__ wq,
        float* __restrict__ sw) {
    const int row = blockIdx.x, t = threadIdx.x;
    const float* wr = w + (size_t)row * 4096;
    float4 v[4];
#pragma unroll
    for (int i = 0; i < 4; i++)
        v[i] = *(const float4*)(wr + t * 16 + i * 4);
    float m = 0.0f;
#pragma unroll
    for (int i = 0; i < 4; i++)
        m = fmaxf(m, fmaxf(fmaxf(fabsf(v[i].x), fabsf(v[i].y)),
                           fmaxf(fabsf(v[i].z), fabsf(v[i].w))));
#pragma unroll
    for (int off = 1; off < 64; off <<= 1)
        m = fmaxf(m, __shfl_xor(m, off));
    __shared__ float wm[4];
    if ((t & 63) == 0) wm[t >> 6] = m;
    __syncthreads();
    m = fmaxf(fmaxf(wm[0], wm[1]), fmaxf(wm[2], wm[3]));
    const float scale = fmaxf(m / 127.0f, 1e-8f);
    if (t == 0) sw[row] = scale;
    const float inv = 1.0f / scale;
    union { int8_t b[16]; i32x4 w4; } o;
#pragma unroll
    for (int i = 0; i < 4; i++) {
        o.b[i * 4 + 0] = q8m(v[i].x, inv);
        o.b[i * 4 + 1] = q8m(v[i].y, inv);
        o.b[i * 4 + 2] = q8m(v[i].z, inv);
        o.b[i * 4 + 3] = q8m(v[i].w, inv);
    }
    *(i32x4*)(wq + (size_t)row * 4096 + t * 16) = o.w4;
}

// ---------------- int8 GEMM: 128x128, compute-covered DMA ------------------
// LDS image: row r (128 rows, 128 B), 16B chunk c at byte r*128 + (c^(r&7))*16
// (staging lanes fetch permuted global chunks; DMA dest linear).
// Buffer holds tile j at iter-j start. Iter j:
//   {ds_read tile j -> regs; __syncthreads (all reads retired);
//    stage-issue tile j+1 (8 DMA, overwrites buffer) + sx(j+1) reg prefetch;
//    MFMA+fold tile j (covers DMA flight); __syncthreads (vmcnt0 drain)}.
#define ITER(SXC, SXN, J)                                                    \
    {                                                                        \
        i32x4 a[4][2], b[4][2];                                              \
        _Pragma("unroll")                                                    \
        for (int mi = 0; mi < 4; ++mi) {                                     \
            const int arow = wm + mi * 16 + fr;                              \
            const int brow = wn + mi * 16 + fr;                              \
            _Pragma("unroll")                                                \
            for (int h = 0; h < 2; ++h) {                                    \
                a[mi][h] = *(const i32x4*)(As + arow * 128 +                 \
                                           (((h * 4 + q) ^ r7) << 4));       \
                b[mi][h] = *(const i32x4*)(Bs + brow * 128 +                 \
                                           (((h * 4 + q) ^ r7) << 4));       \
            }                                                                \
        }                                                                    \
        __syncthreads(); /* all waves' reads of tile J retired */            \
        const int jn = ((J) + 1 < NT) ? (J) + 1 : (J);                       \
        const size_t kn = (size_t)jn << 7;                                   \
        load_lds16(Ag + kn,            As + sldsw);                          \
        load_lds16(Ag + kn + 32 * sK,  As + 32 * 128 + sldsw);               \
        load_lds16(Ag + kn + 64 * sK,  As + 64 * 128 + sldsw);               \
        load_lds16(Ag + kn + 96 * sK,  As + 96 * 128 + sldsw);               \
        load_lds16(Bg + kn,            Bs + sldsw);                          \
        load_lds16(Bg + kn + 32 * sK,  Bs + 32 * 128 + sldsw);               \
        load_lds16(Bg + kn + 64 * sK,  Bs + 64 * 128 + sldsw);               \
        load_lds16(Bg + kn + 96 * sK,  Bs + 96 * 128 + sldsw);               \
        _Pragma("unroll")                                                    \
        for (int mi = 0; mi < 4; ++mi)                                       \
            SXN[mi] = *(const f32x4*)(sxg + (size_t)jn * M + mi * 16);       \
        __builtin_amdgcn_sched_barrier(0); /* keep issues ahead of MFMA */   \
        _Pragma("unroll")                                                    \
        for (int ni = 0; ni < 4; ++ni) {                                     \
            i32x4 it[4];                                                     \
            _Pragma("unroll")                                                \
            for (int mi = 0; mi < 4; ++mi) {                                 \
                it[mi] = __builtin_amdgcn_mfma_i32_16x16x64_i8(              \
                    a[mi][0], b[ni][0], (i32x4){0, 0, 0, 0}, 0, 0, 0);       \
                it[mi] = __builtin_amdgcn_mfma_i32_16x16x64_i8(              \
                    a[mi][1], b[ni][1], it[mi], 0, 0, 0);                    \
            }                                                                \
            _Pragma("unroll")                                                \
            for (int mi = 0; mi < 4; ++mi)                                   \
                _Pragma("unroll")                                            \
                for (int r = 0; r < 4; ++r)                                  \
                    acc[mi][ni][r] += (float)it[mi][r] * SXC[mi][r];         \
        }                                                                    \
        __syncthreads(); /* drains vmcnt(0): tile jn landed, DMA covered */  \
    }

__global__ __launch_bounds__(256, 2) void gemm_i8_kernel(
        const int8_t* __restrict__ A, const int8_t* __restrict__ B,
        const float* __restrict__ sxT, const float* __restrict__ sw,
        const float* __restrict__ bias, float* __restrict__ C,
        int M, int N, int K) {
    __shared__ __align__(16) int8_t As[128 * 128];   // 16 KB
    __shared__ __align__(16) int8_t Bs[128 * 128];   // 16 KB
    const int tid = threadIdx.x;
    const int wave = tid >> 6, lane = tid & 63;
    const int bm = blockIdx.y * 128, bn = blockIdx.x * 128;  // 2D grid (R3)
    const int wm = (wave >> 1) << 6, wn = (wave & 1) << 6;   // 64x64 / wave
    const int fr = lane & 15, q = lane >> 4, r7 = lane & 7;

    // staging: call i covers rows i*32 + wave*8 + (lane>>3);
    // lane fetches global chunk (lane&7)^((lane>>3)&7) -> XOR-swizzled LDS.
    const int srow = wave * 8 + (lane >> 3);
    const int scol = ((lane & 7) ^ ((lane >> 3) & 7)) << 4;
    const size_t sK = (size_t)K;
    const int8_t* Ag = A + (size_t)(bm + srow) * sK + scol;
    const int8_t* Bg = B + (size_t)(bn + srow) * sK + scol;
    const int sldsw = wave * 8 * 128;   // wave-uniform LDS base per call

    f32x4 acc[4][4];
#pragma unroll
    for (int i = 0; i < 4; i++)
#pragma unroll
        for (int jn2 = 0; jn2 < 4; jn2++)
            acc[i][jn2] = (f32x4){0.f, 0.f, 0.f, 0.f};

    const float* sxg = sxT + bm + wm + q * 4;   // + j*M per tile
    const int NT = K >> 7;

    // prologue: stage tile 0; load sx(0); drain
    load_lds16(Ag,            As + sldsw);
    load_lds16(Ag + 32 * sK,  As + 32 * 128 + sldsw);
    load_lds16(Ag + 64 * sK,  As + 64 * 128 + sldsw);
    load_lds16(Ag + 96 * sK,  As + 96 * 128 + sldsw);
    load_lds16(Bg,            Bs + sldsw);
    load_lds16(Bg + 32 * sK,  Bs + 32 * 128 + sldsw);
    load_lds16(Bg + 64 * sK,  Bs + 64 * 128 + sldsw);
    load_lds16(Bg + 96 * sK,  Bs + 96 * 128 + sldsw);
    f32x4 sxa[4], sxb[4];
#pragma unroll
    for (int mi = 0; mi < 4; ++mi)
        sxa[mi] = *(const f32x4*)(sxg + mi * 16);
    __syncthreads();   // drains vmcnt: tile 0 + sx(0) resident

    for (int j = 0; j < NT; j += 2) {   // NT = 32, even
        ITER(sxa, sxb, j)
        ITER(sxb, sxa, j + 1)
    }

    // epilogue: C/D layout col=lane&15, row=(lane>>4)*4+reg; fold sw + bias
    const int or0 = bm + wm + q * 4;
    const int oc0 = bn + wn + fr;
    float swv[4], bv[4];
#pragma unroll
    for (int ni = 0; ni < 4; ni++) {
        swv[ni] = sw[oc0 + ni * 16];
        bv[ni] = bias[oc0 + ni * 16];
    }
#pragma unroll
    for (int mi = 0; mi < 4; mi++)
#pragma unroll
        for (int ni = 0; ni < 4; ni++)
#pragma unroll
            for (int r = 0; r < 4; r++)
                C[(size_t)(or0 + mi * 16 + r) * N + (oc0 + ni * 16)] =
                    acc[mi][ni][r] * swv[ni] + bv[ni];
}

extern "C" void kernel_launch(void* const* d_in, const int* in_sizes, int n_in,
                              void* d_out, int out_size, void* d_ws, size_t ws_size,
                              hipStream_t stream) {
    const float* x    = (const float*)d_in[0];
    const float* w    = (const float*)d_in[1];
    const float* bias = (const float*)d_in[2];
    // d_in[3] = group_size (128) — hard-assumed.

    const int out_f  = in_sizes[2];
    const int in_f   = in_sizes[1] / out_f;   // 4096
    const int tokens = in_sizes[0] / in_f;
    const int G = in_f / 128;

    int8_t* xq  = (int8_t*)d_ws;                         // [M,K] int8
    int8_t* wq  = xq + (size_t)tokens * in_f;            // [N,K] int8
    float*  sxT = (float*)(wq + (size_t)out_f * in_f);   // [G,M] fp32
    float*  sw  = sxT + (size_t)G * tokens;              // [N]  fp32
    float*  out = (float*)d_out;

    quant_act_kernel<<<tokens, 256, 0, stream>>>(x, xq, sxT, tokens);
    quant_wgt_kernel<<<out_f, 256, 0, stream>>>(w, wq, sw);

    dim3 grid(out_f / 128, tokens / 128);   // 2D dispatch, bn fast (R3 order)
    gemm_i8_kernel<<<grid, 256, 0, stream>>>(xq, wq, sxT, sw, bias, out,
                                             tokens, out_f, in_f);
}

// Round 6
// 438.623 us; speedup vs baseline: 1.2774x; 1.1345x over previous
//
#include <hip/hip_runtime.h>
#include <stdint.h>

// ---------------------------------------------------------------------------
// QuantLinear via EXACT int8 path:
//   qx[t,k] int8, sx[t,g] (g=k/128) ; qw[o,k] int8, sw[o]
//   out[t,o] = sw[o] * sum_g sx[t,g] * (int dot over group g) + bias[o]
// R9: operand-SWAPPED GEMM (D rows = weight-o, cols = token-t) so the
// per-group act scale is ONE SCALAR per ni (col=fr carries t) -> scale regs
// 32->8, enabling a 2x-area wave tile (64o x 128t) at <=252 VGPR.
// Block 256t x 128o, 4 waves, BK=128, single 48KB LDS, R3's proven
// drain-early 2-sync loop (every overlap variant R5-R8 regressed), 2D grid.
// bytes/MFMA 768->576, sync events halved. sw/bias fold in epilogue only.
// Quant kernels unchanged.
// ---------------------------------------------------------------------------

typedef __attribute__((ext_vector_type(4))) int   i32x4;
typedef __attribute__((ext_vector_type(4))) float f32x4;

static __device__ __forceinline__ void load_lds16(const void* g, void* l) {
    __builtin_amdgcn_global_load_lds(
        (const __attribute__((address_space(1))) void*)g,
        (__attribute__((address_space(3))) void*)l, 16, 0, 0);
}

static __device__ __forceinline__ int8_t q8m(float v, float inv) {
    float q = rintf(v * inv);                   // half-even, matches np
    q = fminf(fmaxf(q, -128.0f), 127.0f);
    return (int8_t)(int)q;
}

// ---------------- act quant: one row per block -----------------------------
__global__ __launch_bounds__(256) void quant_act_kernel(
        const float* __restrict__ x, int8_t* __restrict__ xq,
        float* __restrict__ sxT, int M) {
    const int row = blockIdx.x, t = threadIdx.x;
    const float* xr = x + (size_t)row * 4096;
    float4 v[4];
#pragma unroll
    for (int i = 0; i < 4; i++)
        v[i] = *(const float4*)(xr + t * 16 + i * 4);
    float m = 0.0f;
#pragma unroll
    for (int i = 0; i < 4; i++)
        m = fmaxf(m, fmaxf(fmaxf(fabsf(v[i].x), fabsf(v[i].y)),
                           fmaxf(fabsf(v[i].z), fabsf(v[i].w))));
    m = fmaxf(m, __shfl_xor(m, 1));
    m = fmaxf(m, __shfl_xor(m, 2));
    m = fmaxf(m, __shfl_xor(m, 4));
    const float scale = fmaxf(m / 127.0f, 1e-8f);
    const float inv = 1.0f / scale;
    union { int8_t b[16]; i32x4 w; } o;
#pragma unroll
    for (int i = 0; i < 4; i++) {
        o.b[i * 4 + 0] = q8m(v[i].x, inv);
        o.b[i * 4 + 1] = q8m(v[i].y, inv);
        o.b[i * 4 + 2] = q8m(v[i].z, inv);
        o.b[i * 4 + 3] = q8m(v[i].w, inv);
    }
    *(i32x4*)(xq + (size_t)row * 4096 + t * 16) = o.w;
    if ((t & 7) == 0)                       // sxT layout [G, M]
        sxT[(size_t)(t >> 3) * M + row] = scale;
}

// ---------------- weight quant: one row per block, per-row scale -----------
__global__ __launch_bounds__(256) void quant_wgt_kernel(
        const float* __restrict__ w, int8_t* __restrict__ wq,
        float* __restrict__ sw) {
    const int row = blockIdx.x, t = threadIdx.x;
    const float* wr = w + (size_t)row * 4096;
    float4 v[4];
#pragma unroll
    for (int i = 0; i < 4; i++)
        v[i] = *(const float4*)(wr + t * 16 + i * 4);
    float m = 0.0f;
#pragma unroll
    for (int i = 0; i < 4; i++)
        m = fmaxf(m, fmaxf(fmaxf(fabsf(v[i].x), fabsf(v[i].y)),
                           fmaxf(fabsf(v[i].z), fabsf(v[i].w))));
#pragma unroll
    for (int off = 1; off < 64; off <<= 1)
        m = fmaxf(m, __shfl_xor(m, off));
    __shared__ float wm[4];
    if ((t & 63) == 0) wm[t >> 6] = m;
    __syncthreads();
    m = fmaxf(fmaxf(wm[0], wm[1]), fmaxf(wm[2], wm[3]));
    const float scale = fmaxf(m / 127.0f, 1e-8f);
    if (t == 0) sw[row] = scale;
    const float inv = 1.0f / scale;
    union { int8_t b[16]; i32x4 w4; } o;
#pragma unroll
    for (int i = 0; i < 4; i++) {
        o.b[i * 4 + 0] = q8m(v[i].x, inv);
        o.b[i * 4 + 1] = q8m(v[i].y, inv);
        o.b[i * 4 + 2] = q8m(v[i].z, inv);
        o.b[i * 4 + 3] = q8m(v[i].w, inv);
    }
    *(i32x4*)(wq + (size_t)row * 4096 + t * 16) = o.w4;
}

// ---------------- int8 GEMM: swapped operands, 256t x 128o -----------------
// LDS image (both tiles): row r, 16B chunk c at byte r*128 + (c^(r&7))*16
// (staging lanes fetch permuted global chunks; DMA dest linear).
// Wave (of 4): wo = (wave&1)*64, wt = (wave>>1)*128. Per K-tile (= 1 group):
//   stage tile j (12 DMA calls) + sx scalars; __syncthreads (vmcnt drain,
//   tile resident); a = wq-frags (resident, 8xb128); two ni-halves of
//   b = xq-frags (8xb128 each, regs reused); 64 MFMA; fold by SCALAR sxs[ni];
//   __syncthreads (reads retired -> next stage safe).
// D mapping: row (q*4+r) = o, col (fr) = t  => sx scalar/lane per ni;
// sw/bias epilogue-only. Store f32x4 per (mi,ni) at C[t*N + o4base].
__global__ __launch_bounds__(256, 2) void gemm_i8_kernel(
        const int8_t* __restrict__ Xq, const int8_t* __restrict__ Wq,
        const float* __restrict__ sxT, const float* __restrict__ sw,
        const float* __restrict__ bias, float* __restrict__ C,
        int M, int N, int K) {
    __shared__ __align__(16) int8_t Ws[128 * 128];   // wq tile (o-rows), 16 KB
    __shared__ __align__(16) int8_t Xs[256 * 128];   // xq tile (t-rows), 32 KB
    const int tid = threadIdx.x;
    const int wave = tid >> 6, lane = tid & 63;
    const int bo = blockIdx.x * 128;     // o-block (fast dim, R3 order)
    const int bt = blockIdx.y * 256;     // t-block
    const int wo = (wave & 1) << 6, wt = (wave >> 1) << 7;  // 64o x 128t
    const int fr = lane & 15, q = lane >> 4, r7 = lane & 7;

    // staging: call i covers rows i*32 + wave*8 + (lane>>3);
    // lane fetches global chunk (lane&7)^((lane>>3)&7) -> XOR-swizzled LDS.
    const int srow = wave * 8 + (lane >> 3);
    const int scol = ((lane & 7) ^ ((lane >> 3) & 7)) << 4;
    const size_t sK = (size_t)K;
    const int8_t* Wg = Wq + (size_t)(bo + srow) * sK + scol;
    const int8_t* Xg = Xq + (size_t)(bt + srow) * sK + scol;
    const int sldsw = wave * 8 * 128;   // wave-uniform LDS base per call

    f32x4 facc[4][8];                   // [mi][ni], 128 VGPR
#pragma unroll
    for (int i = 0; i < 4; i++)
#pragma unroll
        for (int jn = 0; jn < 8; jn++) facc[i][jn] = (f32x4){0.f, 0.f, 0.f, 0.f};

    const float* sxb = sxT + bt + wt + fr;   // + j*M + ni*16 per use
    const int NT = K >> 7;

    for (int j = 0; j < NT; ++j) {
        const size_t k0 = (size_t)j << 7;
        // stage current tile j (buffer fully read last iter; synced below)
#pragma unroll
        for (int i = 0; i < 4; ++i)
            load_lds16(Wg + k0 + (size_t)i * 32 * sK, Ws + i * 32 * 128 + sldsw);
#pragma unroll
        for (int i = 0; i < 8; ++i)
            load_lds16(Xg + k0 + (size_t)i * 32 * sK, Xs + i * 32 * 128 + sldsw);
        // per-group act scales: one scalar per ni (t = col = fr)
        float sxs[8];
#pragma unroll
        for (int ni = 0; ni < 8; ++ni)
            sxs[ni] = sxb[(size_t)j * M + ni * 16];
        __syncthreads();   // drains vmcnt(0)+lgkm: tile j + sxs resident

        i32x4 a[4][2];     // wq-frags, resident across both halves
#pragma unroll
        for (int mi = 0; mi < 4; ++mi) {
            const int arow = (wo + mi * 16 + fr) * 128;
#pragma unroll
            for (int h = 0; h < 2; ++h)
                a[mi][h] = *(const i32x4*)(Ws + arow + (((h * 4 + q) ^ r7) << 4));
        }
#pragma unroll
        for (int half = 0; half < 2; ++half) {
            i32x4 b[4][2];
#pragma unroll
            for (int nj = 0; nj < 4; ++nj) {
                const int brow = (wt + (half * 4 + nj) * 16 + fr) * 128;
#pragma unroll
                for (int h = 0; h < 2; ++h)
                    b[nj][h] = *(const i32x4*)(Xs + brow +
                                               (((h * 4 + q) ^ r7) << 4));
            }
#pragma unroll
            for (int nj = 0; nj < 4; ++nj) {
                const float s = sxs[half * 4 + nj];
                i32x4 it[4];
#pragma unroll
                for (int mi = 0; mi < 4; ++mi) {
                    it[mi] = __builtin_amdgcn_mfma_i32_16x16x64_i8(
                        a[mi][0], b[nj][0], (i32x4){0, 0, 0, 0}, 0, 0, 0);
                    it[mi] = __builtin_amdgcn_mfma_i32_16x16x64_i8(
                        a[mi][1], b[nj][1], it[mi], 0, 0, 0);
                }
#pragma unroll
                for (int mi = 0; mi < 4; ++mi)
#pragma unroll
                    for (int r = 0; r < 4; ++r)
                        facc[mi][half * 4 + nj][r] += (float)it[mi][r] * s;
            }
        }
        __syncthreads();   // all reads retired -> next stage may overwrite
    }

    // epilogue: o = bo+wo+mi*16+q*4+r (acc reg r = consecutive o!),
    // t = bt+wt+ni*16+fr. Fold sw/bias; one 16B store per (mi,ni).
    const int o4 = bo + wo + q * 4;
    f32x4 swv[4], bv[4];
#pragma unroll
    for (int mi = 0; mi < 4; ++mi) {
        swv[mi] = *(const f32x4*)(sw + o4 + mi * 16);
        bv[mi]  = *(const f32x4*)(bias + o4 + mi * 16);
    }
#pragma unroll
    for (int mi = 0; mi < 4; ++mi)
#pragma unroll
        for (int ni = 0; ni < 8; ++ni) {
            f32x4 o;
#pragma unroll
            for (int r = 0; r < 4; ++r)
                o[r] = facc[mi][ni][r] * swv[mi][r] + bv[mi][r];
            const int t = bt + wt + ni * 16 + fr;
            *(f32x4*)(C + (size_t)t * N + o4 + mi * 16) = o;
        }
}

extern "C" void kernel_launch(void* const* d_in, const int* in_sizes, int n_in,
                              void* d_out, int out_size, void* d_ws, size_t ws_size,
                              hipStream_t stream) {
    const float* x    = (const float*)d_in[0];
    const float* w    = (const float*)d_in[1];
    const float* bias = (const float*)d_in[2];
    // d_in[3] = group_size (128) — hard-assumed.

    const int out_f  = in_sizes[2];
    const int in_f   = in_sizes[1] / out_f;   // 4096
    const int tokens = in_sizes[0] / in_f;
    const int G = in_f / 128;

    int8_t* xq  = (int8_t*)d_ws;                         // [M,K] int8
    int8_t* wq  = xq + (size_t)tokens * in_f;            // [N,K] int8
    float*  sxT = (float*)(wq + (size_t)out_f * in_f);   // [G,M] fp32
    float*  sw  = sxT + (size_t)G * tokens;              // [N]  fp32
    float*  out = (float*)d_out;

    quant_act_kernel<<<tokens, 256, 0, stream>>>(x, xq, sxT, tokens);
    quant_wgt_kernel<<<out_f, 256, 0, stream>>>(w, wq, sw);

    dim3 grid(out_f / 128, tokens / 256);   // (32, 32), o fast (R3 order)
    gemm_i8_kernel<<<grid, 256, 0, stream>>>(xq, wq, sxT, sw, bias, out,
                                             tokens, out_f, in_f);
}